// Round 4
// baseline (110.952 us; speedup 1.0000x reference)
//
#include <hip/hip_runtime.h>
#include <math.h>

#define PI_F 3.14159265358979323846f

// d_ws layout (floats):
//   [p*32]      : running sum  (own 64B line)
//   [p*32 + 16] : running sum2 (own 64B line)
//   [6272]      : barrier arrive counter (int)
#define SLOT 32
#define CNT_OFF (196 * SLOT)
#define ZERO_BYTES ((196 * SLOT + 16) * 4)   // 25152 B zeroed by memset node

// ---------------------------------------------------------------------------
// Fused persistent kernel, 256 blocks x 512 threads, 16 images/block.
// Software grid barrier (no cooperative API): 256 blocks always co-resident
// (256 <= 256 CUs; even 2-per-CU packing fits 2x58KB in 160KB LDS).
//
// Circuit reduced analytically: RZ diagonals cancel in |amp|^2 (the circuit
// is a monomial matrix); CNOT chain permutes basis (i,j,k,l)->(i,j,k^i,l^j).
//   feats = [cos a0, cos a1, cos a0*cos a2, cos a1*cos a3],
//   a_w = (v_w - mean_p) * pi/(std_p + 1e-6)
// ---------------------------------------------------------------------------
__global__ __launch_bounds__(512, 2) void k_fused(const float* __restrict__ x,
                                                  const float* __restrict__ W,
                                                  const float* __restrict__ bias,
                                                  float* __restrict__ ws,
                                                  float* __restrict__ out) {
    __shared__ __align__(16) float  sW[7840];     // 31360 B raw W [10][784]
    __shared__ __align__(16) float  sx[8 * 784];  // 25088 B, one 8-image chunk
    __shared__ __align__(16) float2 sst[196];     // 1568 B
    __shared__ float sbias[10];

    const int tid = threadIdx.x;
    const int blk = blockIdx.x;

    // ---- stage W + bias (once) ----
    const float4* W4 = (const float4*)W;
    for (int i = tid; i < 1960; i += 512)
        ((float4*)sW)[i] = W4[i];
    if (tid < 10) sbias[tid] = bias[tid];

    // ---- phase 1: per-patch partials over this block's 16 images ----
    const int r    = (tid < 196) ? (tid / 14) : 0;
    const int poff = (tid < 196) ? (2 * tid + 28 * r) : 0;
    float s = 0.f, s2 = 0.f;

    const float4* x4 = (const float4*)x;
    for (int chunk = 0; chunk < 2; chunk++) {
        const int base4 = (blk * 16 + chunk * 8) * 196;
        __syncthreads();                       // protect sx before overwrite
        for (int i = tid; i < 1568; i += 512)
            ((float4*)sx)[i] = x4[base4 + i];
        __syncthreads();
        if (tid < 196) {
#pragma unroll
            for (int i = 0; i < 8; i++) {
                const float* b = sx + i * 784 + poff;
                float v0 = b[0], v1 = b[1], v2 = b[28], v3 = b[29];
                s += (v0 + v1) + (v2 + v3);
                s2 = fmaf(v0, v0, s2); s2 = fmaf(v1, v1, s2);
                s2 = fmaf(v2, v2, s2); s2 = fmaf(v3, v3, s2);
            }
        }
    }
    if (tid < 196) {
        atomicAdd(ws + tid * SLOT, s);
        atomicAdd(ws + tid * SLOT + 16, s2);
        __threadfence();                       // my adds visible before arrive
    }
    __syncthreads();

    // ---- software grid barrier ----
    int* cnt = (int*)(ws + CNT_OFF);
    if (tid == 0) {
        atomicAdd(cnt, 1);
        while (atomicAdd(cnt, 0) < 256)
            __builtin_amdgcn_s_sleep(8);
    }
    __syncthreads();

    // ---- finalize stats (atomic reads = coherence-point reads) ----
    if (tid < 196) {
        float S  = atomicAdd(ws + tid * SLOT, 0.0f);
        float S2 = atomicAdd(ws + tid * SLOT + 16, 0.0f);
        const float N = 16384.0f;
        float mean = S / N;
        float var = fmaxf((S2 - S * mean) / (N - 1.0f), 0.f);
        sst[tid] = make_float2(mean, PI_F / (sqrtf(var) + 1e-6f));
    }
    __syncthreads();

    // ---- phase 2: features + GEMV + log_softmax, 1 image per wave ----
    const int wave = tid >> 6;
    const int lane = tid & 63;

    for (int chunk = 1; chunk >= 0; chunk--) {   // chunk 1 is already in LDS
        if (chunk == 0) {
            __syncthreads();                     // all waves done with chunk 1
            const int base4 = (blk * 16) * 196;
            for (int i = tid; i < 1568; i += 512)
                ((float4*)sx)[i] = x4[base4 + i];   // L3-hot restage
            __syncthreads();
        }
        const float* img = sx + wave * 784;

        float acc[10];
#pragma unroll
        for (int o = 0; o < 10; o++) acc[o] = 0.f;

        for (int k = 0; k < 13; k++) {
            int f = lane + 64 * k;
            if (f < 784) {
                int p = f >> 2, w = f & 3;
                int pr = p / 14;
                int off = 2 * p + 28 * pr + (w & 1);
                float2 ms = sst[p];
                float feat = __cosf((img[off] - ms.x) * ms.y);
                if (w & 2) feat *= __cosf((img[off + 28] - ms.x) * ms.y);
#pragma unroll
                for (int o = 0; o < 10; o++)
                    acc[o] = fmaf(feat, sW[o * 784 + f], acc[o]);
            }
        }

#pragma unroll
        for (int o = 0; o < 10; o++) {
#pragma unroll
            for (int off = 32; off > 0; off >>= 1)
                acc[o] += __shfl_down(acc[o], off, 64);
        }

        if (lane == 0) {
            float m = -INFINITY;
#pragma unroll
            for (int o = 0; o < 10; o++) { acc[o] += sbias[o]; m = fmaxf(m, acc[o]); }
            float ssum = 0.f;
#pragma unroll
            for (int o = 0; o < 10; o++) ssum += __expf(acc[o] - m);
            float lse = m + __logf(ssum);
            float* op = out + ((size_t)(blk * 16 + chunk * 8 + wave)) * 10;
#pragma unroll
            for (int o = 0; o < 10; o++) op[o] = acc[o] - lse;
        }
    }
}

extern "C" void kernel_launch(void* const* d_in, const int* in_sizes, int n_in,
                              void* d_out, int out_size, void* d_ws, size_t ws_size,
                              hipStream_t stream) {
    const float* x    = (const float*)d_in[0];
    // d_in[1] = params: provably unused (RZ phases cancel in |amp|^2)
    const float* W    = (const float*)d_in[2];
    const float* bias = (const float*)d_in[3];
    float* ws  = (float*)d_ws;
    float* out = (float*)d_out;

    hipMemsetAsync(ws, 0, ZERO_BYTES, stream);   // zero sums + barrier counter
    hipLaunchKernelGGL(k_fused, dim3(256), dim3(512), 0, stream,
                       x, W, bias, ws, out);
}

// Round 5
// 86.989 us; speedup vs baseline: 1.2755x; 1.2755x over previous
//
#include <hip/hip_runtime.h>
#include <math.h>

#define PI_F 3.14159265358979323846f

// d_ws layout (floats): per-patch atomic slots, s and s2 on SEPARATE 128-B
// lines to halve per-line RMW serialization:
//   s  at ws[p*64], s2 at ws[p*64+32]   -> 196*64*4 = 50176 B (memset to 0)
#define SLOT 64
#define ZERO_BYTES (196 * SLOT * 4)

// ---------------------------------------------------------------------------
// Kernel 1: per-patch partial stats. 256 blocks x 16 images. Stage images as
// float4 (coalesced, x read once), 196 threads reduce from LDS via float2,
// then one atomicAdd per (s, s2) to line-separated slots (256 RMWs/line).
// ---------------------------------------------------------------------------
__global__ __launch_bounds__(256) void k_partial(const float* __restrict__ x,
                                                 float* __restrict__ ws) {
    __shared__ __align__(16) float sx[16 * 784];   // 50176 B
    const float4* x4 = (const float4*)x;
    const int base4 = blockIdx.x * (16 * 196);
    for (int i = threadIdx.x; i < 16 * 196; i += 256)
        ((float4*)sx)[i] = x4[base4 + i];
    __syncthreads();
    const int p = threadIdx.x;
    if (p < 196) {
        const int r = p / 14;
        const int off = 2 * p + 28 * r;        // even -> 8B aligned
        float s = 0.f, s2 = 0.f;
#pragma unroll
        for (int i = 0; i < 16; i++) {
            const float* b = sx + i * 784 + off;
            float2 t = *(const float2*)b;
            float2 u = *(const float2*)(b + 28);
            s += (t.x + t.y) + (u.x + u.y);
            s2 = fmaf(t.x, t.x, s2); s2 = fmaf(t.y, t.y, s2);
            s2 = fmaf(u.x, u.x, s2); s2 = fmaf(u.y, u.y, s2);
        }
        atomicAdd(ws + p * SLOT, s);
        atomicAdd(ws + p * SLOT + 32, s2);
    }
}

// ---------------------------------------------------------------------------
// Kernel 2: features + GEMV + log_softmax. 512 blocks x 512 thr, 8 images
// per block (1/wave). Circuit reduced analytically (RZ phases cancel in
// |amp|^2; CNOTs permute basis (i,j,k,l)->(i,j,k^i,l^j)):
//   feats = [cos a0, cos a1, cos a0*cos a2, cos a1*cos a3]
// Patch-per-lane inner loop: 4 cos/patch (minimum), W via ds_read_b128
// (sW[o*784 + 4p] is 16B aligned; lane-consecutive -> full-pump, no conflict).
// LDS = 31360 + 25088 + 1568 + 40 = 58056 B -> 2 blocks/CU, 16 waves/CU.
// ---------------------------------------------------------------------------
__global__ __launch_bounds__(512, 4) void k_main(const float* __restrict__ x,
                                                 const float* __restrict__ W,
                                                 const float* __restrict__ bias,
                                                 const float* __restrict__ ws,
                                                 float* __restrict__ out) {
    __shared__ __align__(16) float  sW[7840];     // raw W [10][784]
    __shared__ __align__(16) float  sx[8 * 784];
    __shared__ __align__(16) float2 sst[196];     // (mean, pi/(std+1e-6))
    __shared__ float sbias[10];

    const int tid = threadIdx.x;
    const float4* W4 = (const float4*)W;
    for (int i = tid; i < 1960; i += 512)
        ((float4*)sW)[i] = W4[i];
    const float4* x4 = (const float4*)(x + (size_t)blockIdx.x * 8 * 784);
    for (int i = tid; i < 1568; i += 512)
        ((float4*)sx)[i] = x4[i];
    if (tid < 196) {
        float s  = ws[tid * SLOT];          // plain loads: HW kernel ordering
        float s2 = ws[tid * SLOT + 32];     // flushes/invalidates caches
        const float N = 16384.0f;
        float mean = s / N;
        float var = fmaxf((s2 - s * mean) / (N - 1.0f), 0.f);
        sst[tid] = make_float2(mean, PI_F / (sqrtf(var) + 1e-6f));
    }
    if (tid < 10) sbias[tid] = bias[tid];
    __syncthreads();

    const int wave = tid >> 6;
    const int lane = tid & 63;
    const float* img = sx + wave * 784;

    float acc[10];
#pragma unroll
    for (int o = 0; o < 10; o++) acc[o] = 0.f;

#pragma unroll
    for (int k = 0; k < 4; k++) {
        const int p = lane + 64 * k;
        if (p < 196) {
            const int r = p / 14;
            const int off = 2 * p + 28 * r;
            float2 t = *(const float2*)(img + off);
            float2 u = *(const float2*)(img + off + 28);
            float2 ms = sst[p];
            float c0 = __cosf((t.x - ms.x) * ms.y);
            float c1 = __cosf((t.y - ms.x) * ms.y);
            float f2 = c0 * __cosf((u.x - ms.x) * ms.y);
            float f3 = c1 * __cosf((u.y - ms.x) * ms.y);
            const float* wp = sW + 4 * p;
#pragma unroll
            for (int o = 0; o < 10; o++) {
                float4 w = *(const float4*)(wp + o * 784);
                float d = fmaf(c0, w.x, fmaf(c1, w.y,
                          fmaf(f2, w.z, f3 * w.w)));
                acc[o] += d;
            }
        }
    }

#pragma unroll
    for (int o = 0; o < 10; o++) {
#pragma unroll
        for (int off = 32; off > 0; off >>= 1)
            acc[o] += __shfl_down(acc[o], off, 64);
    }

    if (lane == 0) {
        float m = -INFINITY;
#pragma unroll
        for (int o = 0; o < 10; o++) { acc[o] += sbias[o]; m = fmaxf(m, acc[o]); }
        float ssum = 0.f;
#pragma unroll
        for (int o = 0; o < 10; o++) ssum += __expf(acc[o] - m);
        float lse = m + __logf(ssum);
        float* op = out + ((size_t)blockIdx.x * 8 + wave) * 10;
#pragma unroll
        for (int o = 0; o < 10; o++) op[o] = acc[o] - lse;
    }
}

extern "C" void kernel_launch(void* const* d_in, const int* in_sizes, int n_in,
                              void* d_out, int out_size, void* d_ws, size_t ws_size,
                              hipStream_t stream) {
    const float* x    = (const float*)d_in[0];
    // d_in[1] = params: provably unused (RZ phases cancel in |amp|^2)
    const float* W    = (const float*)d_in[2];
    const float* bias = (const float*)d_in[3];
    float* ws  = (float*)d_ws;
    float* out = (float*)d_out;

    hipMemsetAsync(ws, 0, ZERO_BYTES, stream);   // zero the atomic slots
    hipLaunchKernelGGL(k_partial, dim3(256), dim3(256), 0, stream, x, ws);
    hipLaunchKernelGGL(k_main, dim3(512), dim3(512), 0, stream,
                       x, W, bias, ws, out);
}

// Round 6
// 81.465 us; speedup vs baseline: 1.3620x; 1.0678x over previous
//
#include <hip/hip_runtime.h>
#include <math.h>

#define PI_F 3.14159265358979323846f

// d_ws layout (floats), NO memset needed (all slots unconditionally written):
//   [0      .. 50176) : partial s  [patch][block]  (196 x 256)
//   [50176  .. 100352): partial s2 [patch][block]
//   [100352 .. 100744): final stats float2[196] = (mean, pi/(std+1e-6))
#define PS_OFF  0
#define PS2_OFF 50176
#define ST_OFF  100352

// ---------------------------------------------------------------------------
// Kernel 1: per-patch partial stats, 256 blocks x 16 images. Stage images as
// float4 (coalesced, x read exactly once), 196 threads reduce their patch
// from LDS, then plain-store (s, s2) into per-block slots. Zero atomics.
// ---------------------------------------------------------------------------
__global__ __launch_bounds__(256) void k_partial(const float* __restrict__ x,
                                                 float* __restrict__ ws) {
    __shared__ __align__(16) float sx[16 * 784];   // 50176 B
    const float4* x4 = (const float4*)x;
    const int base4 = blockIdx.x * (16 * 196);
    for (int i = threadIdx.x; i < 16 * 196; i += 256)
        ((float4*)sx)[i] = x4[base4 + i];
    __syncthreads();
    const int p = threadIdx.x;
    if (p < 196) {
        const int r = p / 14;
        const int off = 2 * p + 28 * r;        // even -> 8B aligned
        float s = 0.f, s2 = 0.f;
#pragma unroll
        for (int i = 0; i < 16; i++) {
            const float* b = sx + i * 784 + off;
            float2 t = *(const float2*)b;
            float2 u = *(const float2*)(b + 28);
            s += (t.x + t.y) + (u.x + u.y);
            s2 = fmaf(t.x, t.x, s2); s2 = fmaf(t.y, t.y, s2);
            s2 = fmaf(u.x, u.x, s2); s2 = fmaf(u.y, u.y, s2);
        }
        ws[PS_OFF  + p * 256 + blockIdx.x] = s;
        ws[PS2_OFF + p * 256 + blockIdx.x] = s2;
    }
}

// ---------------------------------------------------------------------------
// Kernel 2: finalize stats. 196 blocks x 1 wave; block p reduces its
// 256-float partial rows (lane-float4, coalesced), writes float2 stats.
// ---------------------------------------------------------------------------
__global__ __launch_bounds__(64) void k_reduce(float* __restrict__ ws) {
    const int p = blockIdx.x;
    const int lane = threadIdx.x;
    float4 a = ((const float4*)(ws + PS_OFF  + p * 256))[lane];
    float4 b = ((const float4*)(ws + PS2_OFF + p * 256))[lane];
    float s  = (a.x + a.y) + (a.z + a.w);
    float s2 = (b.x + b.y) + (b.z + b.w);
#pragma unroll
    for (int off = 32; off > 0; off >>= 1) {
        s  += __shfl_down(s, off, 64);
        s2 += __shfl_down(s2, off, 64);
    }
    if (lane == 0) {
        const float N = 16384.0f;
        float mean = s / N;
        float var = fmaxf((s2 - s * mean) / (N - 1.0f), 0.f);
        ((float2*)(ws + ST_OFF))[p] =
            make_float2(mean, PI_F / (sqrtf(var) + 1e-6f));
    }
}

// ---------------------------------------------------------------------------
// Kernel 3: features + GEMV + log_softmax. 512 blocks x 512 thr, 8 images
// per block (1/wave). Circuit reduced analytically (RZ phases cancel in
// |amp|^2; CNOTs permute basis (i,j,k,l)->(i,j,k^i,l^j)):
//   feats = [cos a0, cos a1, cos a0*cos a2, cos a1*cos a3]
// Patch-per-lane: 4 cos/patch (minimum), W via ds_read_b128 (16B aligned,
// lane-consecutive). LDS = 58 KB -> 2 blocks/CU, 16 waves/CU.
// ---------------------------------------------------------------------------
__global__ __launch_bounds__(512, 4) void k_main(const float* __restrict__ x,
                                                 const float* __restrict__ W,
                                                 const float* __restrict__ bias,
                                                 const float* __restrict__ ws,
                                                 float* __restrict__ out) {
    __shared__ __align__(16) float  sW[7840];     // raw W [10][784]
    __shared__ __align__(16) float  sx[8 * 784];
    __shared__ __align__(16) float2 sst[196];
    __shared__ float sbias[10];

    const int tid = threadIdx.x;
    const float4* W4 = (const float4*)W;
    for (int i = tid; i < 1960; i += 512)
        ((float4*)sW)[i] = W4[i];
    const float4* x4 = (const float4*)(x + (size_t)blockIdx.x * 8 * 784);
    for (int i = tid; i < 1568; i += 512)
        ((float4*)sx)[i] = x4[i];
    if (tid < 196)
        sst[tid] = ((const float2*)(ws + ST_OFF))[tid];  // HW kernel ordering
    if (tid < 10) sbias[tid] = bias[tid];
    __syncthreads();

    const int wave = tid >> 6;
    const int lane = tid & 63;
    const float* img = sx + wave * 784;

    float acc[10];
#pragma unroll
    for (int o = 0; o < 10; o++) acc[o] = 0.f;

#pragma unroll
    for (int k = 0; k < 4; k++) {
        const int p = lane + 64 * k;
        if (p < 196) {
            const int r = p / 14;
            const int off = 2 * p + 28 * r;
            float2 t = *(const float2*)(img + off);
            float2 u = *(const float2*)(img + off + 28);
            float2 ms = sst[p];
            float c0 = __cosf((t.x - ms.x) * ms.y);
            float c1 = __cosf((t.y - ms.x) * ms.y);
            float f2 = c0 * __cosf((u.x - ms.x) * ms.y);
            float f3 = c1 * __cosf((u.y - ms.x) * ms.y);
            const float* wp = sW + 4 * p;
#pragma unroll
            for (int o = 0; o < 10; o++) {
                float4 w = *(const float4*)(wp + o * 784);
                acc[o] += fmaf(c0, w.x, fmaf(c1, w.y,
                          fmaf(f2, w.z, f3 * w.w)));
            }
        }
    }

#pragma unroll
    for (int o = 0; o < 10; o++) {
#pragma unroll
        for (int off = 32; off > 0; off >>= 1)
            acc[o] += __shfl_down(acc[o], off, 64);
    }

    if (lane == 0) {
        float m = -INFINITY;
#pragma unroll
        for (int o = 0; o < 10; o++) { acc[o] += sbias[o]; m = fmaxf(m, acc[o]); }
        float ssum = 0.f;
#pragma unroll
        for (int o = 0; o < 10; o++) ssum += __expf(acc[o] - m);
        float lse = m + __logf(ssum);
        float* op = out + ((size_t)blockIdx.x * 8 + wave) * 10;
#pragma unroll
        for (int o = 0; o < 10; o++) op[o] = acc[o] - lse;
    }
}

extern "C" void kernel_launch(void* const* d_in, const int* in_sizes, int n_in,
                              void* d_out, int out_size, void* d_ws, size_t ws_size,
                              hipStream_t stream) {
    const float* x    = (const float*)d_in[0];
    // d_in[1] = params: provably unused (RZ phases cancel in |amp|^2)
    const float* W    = (const float*)d_in[2];
    const float* bias = (const float*)d_in[3];
    float* ws  = (float*)d_ws;
    float* out = (float*)d_out;

    hipLaunchKernelGGL(k_partial, dim3(256), dim3(256), 0, stream, x, ws);
    hipLaunchKernelGGL(k_reduce,  dim3(196), dim3(64),  0, stream, ws);
    hipLaunchKernelGGL(k_main,    dim3(512), dim3(512), 0, stream,
                       x, W, bias, ws, out);
}